// Round 9
// baseline (323.330 us; speedup 1.0000x reference)
//
#include <hip/hip_runtime.h>
#include <hip/hip_fp16.h>
#include <math.h>

#define B 2
#define T 2048
#define C 384
#define H 6
#define HD 64
#define BHT (B*H*T)                    // 24576
#define LOGT 7.6246189861593985f       // log(2048)

typedef __half half_t;
typedef _Float16 f16x8 __attribute__((ext_vector_type(8)));
typedef float f32x4 __attribute__((ext_vector_type(4)));

// ---------------- reduction helpers ------------------------------------------
__device__ __forceinline__ float block_reduce_sum(float v) {
    __shared__ float sm[4];
    int lane = threadIdx.x & 63, wid = threadIdx.x >> 6;
#pragma unroll
    for (int o = 32; o > 0; o >>= 1) v += __shfl_down(v, o, 64);
    __syncthreads();
    if (lane == 0) sm[wid] = v;
    __syncthreads();
    return sm[0] + sm[1] + sm[2] + sm[3];
}

__device__ __forceinline__ float wave_allreduce_sum(float v) {
#pragma unroll
    for (int o = 1; o < 64; o <<= 1) v += __shfl_xor(v, o, 64);
    return v;
}

__global__ __launch_bounds__(256) void zerof_kernel(float* __restrict__ p) {
    p[(size_t)blockIdx.x * 256 + threadIdx.x] = 0.f;
}

// ---------------- add_time + layernorm -> f16 rows (stride KP, zero-padded) ---
__global__ __launch_bounds__(256) void addtime_ln_f16(
        const float* __restrict__ src, const float* __restrict__ tptr,
        const float* __restrict__ w, const float* __restrict__ bb,
        _Float16* __restrict__ dst, int KP) {
    const int n = C + 1;               // 385
    int row = blockIdx.x;              // over B*T
    const float* srow = src + (size_t)row * C;
    float tval = tptr[0];
    int i0 = threadIdx.x;
    int i1 = threadIdx.x + 256;
    float v0 = srow[i0];
    bool has1 = (i1 < n);
    float v1 = 0.f;
    if (has1) v1 = (i1 < C) ? srow[i1] : tval;
    float s  = block_reduce_sum(v0 + v1);
    float sq = block_reduce_sum(v0*v0 + v1*v1);
    float mean = s / n;
    float var  = sq / n - mean * mean;
    float rstd = rsqrtf(var + 1e-5f);
    _Float16* drow = dst + (size_t)row * KP;
    drow[i0] = (_Float16)((v0 - mean) * rstd * w[i0] + bb[i0]);
    if (has1) drow[i1] = (_Float16)((v1 - mean) * rstd * w[i1] + bb[i1]);
    else if (i1 < KP) drow[i1] = (_Float16)0.f;
}

// ------- weight convert+transpose: W (K×N fp32) -> Wt (N×KP f16, zero-pad) ----
__global__ __launch_bounds__(256) void convtrans_kernel(const float* __restrict__ W,
        _Float16* __restrict__ Wt, int K, int N, int KP) {
    __shared__ float tile[32][33];
    int k0 = blockIdx.x * 32, n0 = blockIdx.y * 32;
    int tx = threadIdx.x & 31, ty = threadIdx.x >> 5;
#pragma unroll
    for (int i = 0; i < 4; ++i) {
        int k = k0 + ty + i * 8, n = n0 + tx;
        tile[ty + i * 8][tx] = (k < K && n < N) ? W[(size_t)k * N + n] : 0.f;
    }
    __syncthreads();
#pragma unroll
    for (int i = 0; i < 4; ++i) {
        int n = n0 + ty + i * 8, k = k0 + tx;
        if (n < N && k < KP) Wt[(size_t)n * KP + k] = (_Float16)tile[tx][ty + i * 8];
    }
}

// ---------------- LDS A-stage loaders (f16 or f32 source) ---------------------
__device__ __forceinline__ f16x8 load8(const _Float16* p) { return *(const f16x8*)p; }
__device__ __forceinline__ f16x8 load8(const float* p) {
    float4 a = *(const float4*)p, b2 = *(const float4*)(p + 4);
    f16x8 r;
    r[0]=(_Float16)a.x; r[1]=(_Float16)a.y; r[2]=(_Float16)a.z; r[3]=(_Float16)a.w;
    r[4]=(_Float16)b2.x; r[5]=(_Float16)b2.y; r[6]=(_Float16)b2.z; r[7]=(_Float16)b2.w;
    return r;
}

// ---------------- 64² f16 MFMA GEMM (small-N): out = A @ Wt^T + bias ----------
template<int ACT, int QKV, typename AT, typename OUT_T>
__global__ __launch_bounds__(256) void mfma_gemm(
        const AT* __restrict__ A, const _Float16* __restrict__ Wt,
        const float* __restrict__ bias, OUT_T* __restrict__ out,
        int M, int N, int KP) {
    __shared__ __align__(16) _Float16 As[64][40];
    __shared__ __align__(16) _Float16 Bs[64][40];
    int tid = threadIdx.x;
    int lane = tid & 63, wave = tid >> 6;
    int wr = wave >> 1, wc = wave & 1;
    int m0 = blockIdx.y * 64, n0 = blockIdx.x * 64;
    int arow = tid >> 2, seg = tid & 3;
    int lrow = lane & 15, lseg = lane >> 4;
    f32x4 acc[2][2] = {};
    for (int k0 = 0; k0 < KP; k0 += 32) {
        __syncthreads();
        *(f16x8*)&As[arow][seg * 8] = load8(&A[(size_t)(m0 + arow) * KP + k0 + seg * 8]);
        *(f16x8*)&Bs[arow][seg * 8] = *(const f16x8*)&Wt[(size_t)(n0 + arow) * KP + k0 + seg * 8];
        __syncthreads();
        f16x8 af[2], bf[2];
#pragma unroll
        for (int i = 0; i < 2; ++i) af[i] = *(const f16x8*)&As[wr*32 + i*16 + lrow][lseg*8];
#pragma unroll
        for (int j = 0; j < 2; ++j) bf[j] = *(const f16x8*)&Bs[wc*32 + j*16 + lrow][lseg*8];
#pragma unroll
        for (int i = 0; i < 2; ++i)
#pragma unroll
            for (int j = 0; j < 2; ++j)
                acc[i][j] = __builtin_amdgcn_mfma_f32_16x16x32_f16(af[i], bf[j], acc[i][j], 0, 0, 0);
    }
    int lcol = lane & 15, lr4 = (lane >> 4) * 4;
#pragma unroll
    for (int i = 0; i < 2; ++i)
#pragma unroll
        for (int j = 0; j < 2; ++j) {
            int col = n0 + wc * 32 + j * 16 + lcol;
            float bv = bias[col];
#pragma unroll
            for (int r = 0; r < 4; ++r) {
                int row = m0 + wr * 32 + i * 16 + lr4 + r;
                float v = acc[i][j][r] + bv;
                if (ACT == 1) v = 0.5f * v * (1.f + erff(v * 0.70710678118654752f));
                if (QKV) {
                    int wq = col / C;
                    int rem = col - wq * C;
                    int hh = rem >> 6, dd = rem & 63;
                    int bb2 = row >> 11, tt = row & 2047;
                    out[(((size_t)wq * (B*H) + bb2 * H + hh) * T + tt) * 64 + dd] = (OUT_T)v;
                } else {
                    out[(size_t)row * N + col] = (OUT_T)v;
                }
            }
        }
}

// ---------------- 128² f16 MFMA GEMM (large-N): 4 waves, 64×64/wave -----------
template<int ACT, int QKV, typename AT, typename OUT_T>
__global__ __launch_bounds__(256) void mfma_gemm128(
        const AT* __restrict__ A, const _Float16* __restrict__ Wt,
        const float* __restrict__ bias, OUT_T* __restrict__ out,
        int M, int N, int KP) {
    __shared__ __align__(16) _Float16 As[128][40];
    __shared__ __align__(16) _Float16 Bs[128][40];
    int tid = threadIdx.x;
    int lane = tid & 63, wave = tid >> 6;
    int wr = wave >> 1, wc = wave & 1;
    int m0 = blockIdx.y * 128, n0 = blockIdx.x * 128;
    int lrow = lane & 15, lseg = lane >> 4;
    f32x4 acc[4][4] = {};
    for (int k0 = 0; k0 < KP; k0 += 32) {
        __syncthreads();
#pragma unroll
        for (int it = 0; it < 2; ++it) {
            int r = (tid >> 2) + it * 64, sg = tid & 3;
            *(f16x8*)&As[r][sg * 8] = load8(&A[(size_t)(m0 + r) * KP + k0 + sg * 8]);
            *(f16x8*)&Bs[r][sg * 8] = *(const f16x8*)&Wt[(size_t)(n0 + r) * KP + k0 + sg * 8];
        }
        __syncthreads();
        f16x8 af[4], bf[4];
#pragma unroll
        for (int i = 0; i < 4; ++i) af[i] = *(const f16x8*)&As[wr*64 + i*16 + lrow][lseg*8];
#pragma unroll
        for (int j = 0; j < 4; ++j) bf[j] = *(const f16x8*)&Bs[wc*64 + j*16 + lrow][lseg*8];
#pragma unroll
        for (int i = 0; i < 4; ++i)
#pragma unroll
            for (int j = 0; j < 4; ++j)
                acc[i][j] = __builtin_amdgcn_mfma_f32_16x16x32_f16(af[i], bf[j], acc[i][j], 0, 0, 0);
    }
    int lcol = lane & 15, lr4 = (lane >> 4) * 4;
#pragma unroll
    for (int i = 0; i < 4; ++i)
#pragma unroll
        for (int j = 0; j < 4; ++j) {
            int col = n0 + wc * 64 + j * 16 + lcol;
            float bv = bias[col];
#pragma unroll
            for (int r = 0; r < 4; ++r) {
                int row = m0 + wr * 64 + i * 16 + lr4 + r;
                float v = acc[i][j][r] + bv;
                if (ACT == 1) v = 0.5f * v * (1.f + erff(v * 0.70710678118654752f));
                if (QKV) {
                    int wq = col / C;
                    int rem = col - wq * C;
                    int hh = rem >> 6, dd = rem & 63;
                    int bb2 = row >> 11, tt = row & 2047;
                    out[(((size_t)wq * (B*H) + bb2 * H + hh) * T + tt) * 64 + dd] = (OUT_T)v;
                } else {
                    out[(size_t)row * N + col] = (OUT_T)v;
                }
            }
        }
}

// ------- qk tile pass: one block per lower-triangle (qt,jt) tile --------------
__global__ __launch_bounds__(256) void qk_tileA(const _Float16* __restrict__ qh,
        const _Float16* __restrict__ kh, half_t* __restrict__ c_h) {
    int p = blockIdx.x, bh = blockIdx.y;
    int qt = (int)((sqrtf(8.f * (float)p + 1.f) - 1.f) * 0.5f);
    while ((qt + 1) * (qt + 2) / 2 <= p) ++qt;
    while (qt * (qt + 1) / 2 > p) --qt;
    int jt = p - qt * (qt + 1) / 2;
    int tid = threadIdx.x, lane = tid & 63, wave = tid >> 6;
    int wr = wave >> 1, wc = wave & 1;
    int lrow = lane & 15, lseg = lane >> 4;
    int orow = (lane >> 4) * 4, ocol = lane & 15;
    __shared__ __align__(16) _Float16 Qs[64][72];
    __shared__ __align__(16) _Float16 Ks[64][72];
    const _Float16* qb = qh + ((size_t)bh * T + qt * 64) * 64;
    const _Float16* kb = kh + ((size_t)bh * T + jt * 64) * 64;
#pragma unroll
    for (int k = 0; k < 2; ++k) {
        int cc = k * 256 + tid;
        int r = cc >> 3, sg = cc & 7;
        *(f16x8*)&Qs[r][sg*8] = *(const f16x8*)&qb[r*64 + sg*8];
        *(f16x8*)&Ks[r][sg*8] = *(const f16x8*)&kb[r*64 + sg*8];
    }
    __syncthreads();
    f32x4 acc[2][2] = {};
    f16x8 af[2], bf[2];
#pragma unroll
    for (int i = 0; i < 2; ++i) af[i] = *(const f16x8*)&Qs[wr*32+i*16+lrow][lseg*8];
#pragma unroll
    for (int j = 0; j < 2; ++j) bf[j] = *(const f16x8*)&Ks[wc*32+j*16+lrow][lseg*8];
#pragma unroll
    for (int i = 0; i < 2; ++i)
#pragma unroll
        for (int j = 0; j < 2; ++j)
            acc[i][j] = __builtin_amdgcn_mfma_f32_16x16x32_f16(af[i], bf[j], acc[i][j], 0,0,0);
#pragma unroll
    for (int i = 0; i < 2; ++i) af[i] = *(const f16x8*)&Qs[wr*32+i*16+lrow][32+lseg*8];
#pragma unroll
    for (int j = 0; j < 2; ++j) bf[j] = *(const f16x8*)&Ks[wc*32+j*16+lrow][32+lseg*8];
#pragma unroll
    for (int i = 0; i < 2; ++i)
#pragma unroll
        for (int j = 0; j < 2; ++j)
            acc[i][j] = __builtin_amdgcn_mfma_f32_16x16x32_f16(af[i], bf[j], acc[i][j], 0,0,0);
    __syncthreads();                   // Ks reads done -> reuse as staging
    bool diag = (qt == jt);
#pragma unroll
    for (int i = 0; i < 2; ++i)
#pragma unroll
        for (int r = 0; r < 4; ++r) {
            int rl = wr*32 + i*16 + orow + r;
#pragma unroll
            for (int j = 0; j < 2; ++j) {
                int cl = wc*32 + j*16 + ocol;
                float s = acc[i][j][r] * 0.125f;
                float e = (diag && cl > rl) ? 0.f : __expf(s);
                Ks[rl][cl] = (_Float16)e;
            }
        }
    __syncthreads();
    half_t* cb = c_h + ((size_t)bh * T + qt * 64) * T + jt * 64;
#pragma unroll
    for (int k = 0; k < 2; ++k) {
        int cc = k * 256 + tid;
        int r = cc >> 3, sg = cc & 7;
        *(uint4*)&cb[(size_t)r * T + sg*8] = *(const uint4*)&Ks[r][sg*8];
    }
}

// ---- FUSED: normalize rows (q=exp(p)), eu0, and col-accumulate q^T·eu0 -------
// grid (64, B*H): big-qt-first scheduling; 4 waves × 8 rows of half a tile.
__global__ __launch_bounds__(256) void norm_q_col(half_t* __restrict__ c_h,
        float* __restrict__ eu, float* __restrict__ cacc) {
    int qt = 31 - (blockIdx.x >> 1), half = blockIdx.x & 1, bh = blockIdx.y;
    int tid = threadIdx.x, lane = tid & 63, w = tid >> 6;
    int span = (qt + 1) * 64, nch = span >> 3;
    __shared__ float colacc[4][2048];
    float acc32[32];
#pragma unroll
    for (int k = 0; k < 32; ++k) acc32[k] = 0.f;
    half_t* cb = c_h + ((size_t)bh * T + qt * 64 + half * 32) * T;
    for (int rr = 0; rr < 8; ++rr) {
        int i = w * 8 + rr;            // row within half-tile
        half_t* crow = cb + (size_t)i * T;
        uint4 raw[4];
        float z = 0.f;
#pragma unroll
        for (int k = 0; k < 4; ++k) {
            int ch = lane + (k << 6);
            if (ch < nch) {
                uint4 rw = *(const uint4*)(crow + ch * 8);
                raw[k] = rw;
                const __half2* h2 = (const __half2*)&rw;
#pragma unroll
                for (int pp = 0; pp < 4; ++pp) {
                    float2 cf = __half22float2(h2[pp]);
                    z += cf.x + cf.y;
                }
            }
        }
        z = wave_allreduce_sum(z);
        float inv = 1.f / z;
        float qv[32];
        float S = 0.f;
#pragma unroll
        for (int k = 0; k < 4; ++k) {
            int ch = lane + (k << 6);
            if (ch < nch) {
                const __half2* h2 = (const __half2*)&raw[k];
                union { __half2 h[4]; uint4 u; } ou;
#pragma unroll
                for (int pp = 0; pp < 4; ++pp) {
                    float2 cf = __half22float2(h2[pp]);
                    float q0 = __expf(cf.x * inv), q1 = __expf(cf.y * inv);
                    S += q0 + q1;
                    qv[k*8+pp*2] = q0; qv[k*8+pp*2+1] = q1;
                    ou.h[pp] = __floats2half2_rn(q0, q1);
                }
                *(uint4*)(crow + ch * 8) = ou.u;
            }
        }
        S = wave_allreduce_sum(S);
        float eui = 1.f / (2048.f * (S + (float)(T - span)));
        if (lane == 0) eu[(size_t)bh * T + qt * 64 + half * 32 + i] = eui;
#pragma unroll
        for (int k = 0; k < 4; ++k) {
            int ch = lane + (k << 6);
            if (ch < nch)
#pragma unroll
                for (int e = 0; e < 8; ++e)
                    acc32[k*8+e] = fmaf(qv[k*8+e], eui, acc32[k*8+e]);
        }
    }
#pragma unroll
    for (int k = 0; k < 4; ++k) {
        int ch = lane + (k << 6);
        if (ch < nch)
#pragma unroll
            for (int e = 0; e < 8; ++e)
                colacc[w][ch*8+e] = acc32[k*8+e];
    }
    __syncthreads();
    for (int j = tid; j < span; j += 256)
        atomicAdd(&cacc[(size_t)bh*T + j],
                  colacc[0][j]+colacc[1][j]+colacc[2][j]+colacc[3][j]);
}

// ---- FUSED row+col: eu_i = 1/(T(Σq·ev + tail)); cacc += q^T·eu ---------------
__global__ __launch_bounds__(256) void row_col(const half_t* __restrict__ c_h,
        const float* __restrict__ ev, const float* __restrict__ sev,
        float* __restrict__ eu, float* __restrict__ cacc) {
    int qt = 31 - (blockIdx.x >> 1), half = blockIdx.x & 1, bh = blockIdx.y;
    int tid = threadIdx.x, lane = tid & 63, w = tid >> 6;
    int span = (qt + 1) * 64, nch = span >> 3;
    __shared__ float colacc[4][2048];
    float evreg[32], acc32[32];
#pragma unroll
    for (int k = 0; k < 32; ++k) acc32[k] = 0.f;
    const float* evb = ev + (size_t)bh * T;
#pragma unroll
    for (int k = 0; k < 4; ++k) {
        int ch = lane + (k << 6);
        if (ch < nch) {
            float4 e0 = *(const float4*)(evb + ch*8);
            float4 e1 = *(const float4*)(evb + ch*8 + 4);
            evreg[k*8+0]=e0.x; evreg[k*8+1]=e0.y; evreg[k*8+2]=e0.z; evreg[k*8+3]=e0.w;
            evreg[k*8+4]=e1.x; evreg[k*8+5]=e1.y; evreg[k*8+6]=e1.z; evreg[k*8+7]=e1.w;
        }
    }
    float tail = sev[bh*33 + qt + 1];
    const half_t* cb = c_h + ((size_t)bh * T + qt * 64 + half * 32) * T;
    for (int rr = 0; rr < 8; ++rr) {
        int i = w * 8 + rr;
        const half_t* crow = cb + (size_t)i * T;
        uint4 raw[4];
        float s = 0.f;
#pragma unroll
        for (int k = 0; k < 4; ++k) {
            int ch = lane + (k << 6);
            if (ch < nch) {
                uint4 rw = *(const uint4*)(crow + ch * 8);
                raw[k] = rw;
                const __half2* h2 = (const __half2*)&rw;
#pragma unroll
                for (int pp = 0; pp < 4; ++pp) {
                    float2 cf = __half22float2(h2[pp]);
                    s = fmaf(cf.x, evreg[k*8+pp*2],   s);
                    s = fmaf(cf.y, evreg[k*8+pp*2+1], s);
                }
            }
        }
        s = wave_allreduce_sum(s);
        float eui = 1.f / (2048.f * (s + tail));
        if (lane == 0) eu[(size_t)bh * T + qt * 64 + half * 32 + i] = eui;
#pragma unroll
        for (int k = 0; k < 4; ++k) {
            int ch = lane + (k << 6);
            if (ch < nch) {
                const __half2* h2 = (const __half2*)&raw[k];
#pragma unroll
                for (int pp = 0; pp < 4; ++pp) {
                    float2 cf = __half22float2(h2[pp]);
                    acc32[k*8+pp*2]   = fmaf(cf.x, eui, acc32[k*8+pp*2]);
                    acc32[k*8+pp*2+1] = fmaf(cf.y, eui, acc32[k*8+pp*2+1]);
                }
            }
        }
    }
#pragma unroll
    for (int k = 0; k < 4; ++k) {
        int ch = lane + (k << 6);
        if (ch < nch)
#pragma unroll
            for (int e = 0; e < 8; ++e)
                colacc[w][ch*8+e] = acc32[k*8+e];
    }
    __syncthreads();
    for (int j = tid; j < span; j += 256)
        atomicAdd(&cacc[(size_t)bh*T + j],
                  colacc[0][j]+colacc[1][j]+colacc[2][j]+colacc[3][j]);
}

// ---- v-finalize (per bh): ev = 1/(T(cacc+prefix(eu))); sev suffix; cacc=0 ----
__global__ __launch_bounds__(256) void v_fin_full(float* __restrict__ cacc,
        const float* __restrict__ eu, float* __restrict__ ev,
        float* __restrict__ sev) {
    int bh = blockIdx.x;
    int tid = threadIdx.x;
    __shared__ float part[256];
    __shared__ float pre[33];
    __shared__ float ts2[32];
    const float* eub = eu + (size_t)bh * T;
    float* caccb = cacc + (size_t)bh * T;
    float* evb = ev + (size_t)bh * T;
    float a = 0.f;
#pragma unroll
    for (int e = 0; e < 8; ++e) a += eub[tid*8 + e];
    part[tid] = a;
    __syncthreads();
    if (tid == 0) {
        float run = 0.f;
        for (int kt = 0; kt < 32; ++kt) {
            pre[kt] = run;
            float t0 = 0.f;
            for (int k = 0; k < 8; ++k) t0 += part[kt*8 + k];
            run += t0;
        }
        pre[32] = run;
    }
    __syncthreads();
    float p = pre[tid >> 3];           // tile of j = tid*8 .. tid*8+7
    float b2 = 0.f;
#pragma unroll
    for (int e = 0; e < 8; ++e) {
        int j = tid*8 + e;
        float vj = 1.f / (2048.f * (caccb[j] + p));
        evb[j] = vj;
        caccb[j] = 0.f;
        b2 += vj;
    }
    part[tid] = b2;
    __syncthreads();
    if (tid < 32) {
        float t0 = 0.f;
#pragma unroll
        for (int k = 0; k < 8; ++k) t0 += part[tid*8 + k];
        ts2[tid] = t0;
    }
    __syncthreads();
    if (tid == 0) {
        float run = 0.f;
        sev[bh*33 + 32] = 0.f;
        for (int kt = 31; kt >= 0; --kt) { run += ts2[kt]; sev[bh*33 + kt] = run; }
    }
}

// ---------------- Wsuf[kt][d] = sum_{tiles jt>=kt} sum_j ev_j V[j][d] ---------
__global__ __launch_bounds__(256) void wv_suffix_kernel(const _Float16* __restrict__ vh,
        const float* __restrict__ ev, float* __restrict__ wsuf) {
    int bh = blockIdx.x;
    int tid = threadIdx.x;
    int d = tid & 63, g = tid >> 6;
    __shared__ float evs[2048];
    __shared__ float W[32][64];
    __shared__ float red[4][64];
    const float* vb = ev + (size_t)bh * T;
#pragma unroll
    for (int k = 0; k < 8; ++k) evs[tid + k*256] = vb[tid + k*256];
    __syncthreads();
    const _Float16* vbase = vh + (size_t)bh * T * 64;
    for (int jt = 0; jt < 32; ++jt) {
        float a = 0.f;
#pragma unroll
        for (int jj = 0; jj < 16; ++jj) {
            int j = jt*64 + g*16 + jj;
            a += evs[j] * (float)vbase[(size_t)j * 64 + d];
        }
        red[g][d] = a;
        __syncthreads();
        if (g == 0) W[jt][d] = red[0][d] + red[1][d] + red[2][d] + red[3][d];
        __syncthreads();
    }
    if (tid < 64) {
        float run = 0.f;
        wsuf[((size_t)bh*33 + 32)*64 + tid] = 0.f;
        for (int kt = 31; kt >= 0; --kt) {
            run += W[kt][tid];
            wsuf[((size_t)bh*33 + kt)*64 + tid] = run;
        }
    }
}

// ---------------- pv split-K: P = q * (eu*T) * ev, MFMA, f32 atomic accum -----
__global__ __launch_bounds__(256) void pv_split(const half_t* __restrict__ c_h,
        const float* __restrict__ eu, const float* __restrict__ ev,
        const _Float16* __restrict__ vh, const float* __restrict__ wsuf,
        float* __restrict__ y32) {
    int qt = (T/64 - 1) - blockIdx.x, kc = blockIdx.y, bh = blockIdx.z;
    int j0 = kc * 8;
    if (j0 > qt) return;
    int jend = min(qt + 1, j0 + 8);
    int b = bh / H, h = bh - b * H;
    int tid = threadIdx.x, lane = tid & 63, wave = tid >> 6;
    int wr = wave >> 1, wc = wave & 1;
    int lrow = lane & 15, lseg = lane >> 4;
    int orow = (lane >> 4) * 4, ocol = lane & 15;
    __shared__ __align__(16) _Float16 Ps[64][72];
    __shared__ __align__(16) _Float16 Vt[64][72];
    __shared__ float facs[64], vs[64], wsf[64];
    if (tid < 64) {
        facs[tid] = eu[(size_t)bh*T + qt*64 + tid] * 2048.f;
        if (kc == 0) wsf[tid] = wsuf[((size_t)bh*33 + qt + 1)*64 + tid];
    }
    f32x4 acc[2][2] = {};
    const half_t* cb0 = c_h + ((size_t)bh*T + qt*64)*T;
    for (int jt = j0; jt < jend; ++jt) {
        __syncthreads();
        if (tid < 64) vs[tid] = ev[(size_t)bh*T + jt*64 + tid];
        __syncthreads();
        // stage P = q * fac_r * ev_j, f16
#pragma unroll
        for (int k = 0; k < 2; ++k) {
            int cc = k*256 + tid;
            int r = cc >> 3, sg = cc & 7;
            uint4 rw = *(const uint4*)&cb0[(size_t)r*T + jt*64 + sg*8];
            const __half2* h2 = (const __half2*)&rw;
            float fr = facs[r];
            f16x8 p8;
#pragma unroll
            for (int pp = 0; pp < 4; ++pp) {
                float2 cf = __half22float2(h2[pp]);
                p8[pp*2]   = (_Float16)(cf.x * fr * vs[sg*8 + pp*2]);
                p8[pp*2+1] = (_Float16)(cf.y * fr * vs[sg*8 + pp*2 + 1]);
            }
            *(f16x8*)&Ps[r][sg*8] = p8;
        }
        // stage V^T: conflict-free b16 writes
        {
            const _Float16* vb = vh + ((size_t)bh*T + jt*64)*64;
#pragma unroll
            for (int k = 0; k < 2; ++k) {
                int d8 = (wave*2 + k) * 8;
                f16x8 v8 = *(const f16x8*)&vb[(size_t)lane*64 + d8];
#pragma unroll
                for (int e = 0; e < 8; ++e) Vt[d8 + e][lane] = v8[e];
            }
        }
        __syncthreads();
        f16x8 af[2], bf[2];
#pragma unroll
        for (int i = 0; i < 2; ++i) af[i] = *(const f16x8*)&Ps[wr*32+i*16+lrow][lseg*8];
#pragma unroll
        for (int j = 0; j < 2; ++j) bf[j] = *(const f16x8*)&Vt[wc*32+j*16+lrow][lseg*8];
#pragma unroll
        for (int i = 0; i < 2; ++i)
#pragma unroll
            for (int j = 0; j < 2; ++j)
                acc[i][j] = __builtin_amdgcn_mfma_f32_16x16x32_f16(af[i], bf[j], acc[i][j], 0,0,0);
#pragma unroll
        for (int i = 0; i < 2; ++i) af[i] = *(const f16x8*)&Ps[wr*32+i*16+lrow][32+lseg*8];
#pragma unroll
        for (int j = 0; j < 2; ++j) bf[j] = *(const f16x8*)&Vt[wc*32+j*16+lrow][32+lseg*8];
#pragma unroll
        for (int i = 0; i < 2; ++i)
#pragma unroll
            for (int j = 0; j < 2; ++j)
                acc[i][j] = __builtin_amdgcn_mfma_f32_16x16x32_f16(af[i], bf[j], acc[i][j], 0,0,0);
    }
#pragma unroll
    for (int i = 0; i < 2; ++i)
#pragma unroll
        for (int j = 0; j < 2; ++j)
#pragma unroll
            for (int r = 0; r < 4; ++r) {
                int rl = wr*32 + i*16 + orow + r;
                int cl = wc*32 + j*16 + ocol;
                float val = acc[i][j][r];
                if (kc == 0) val += facs[rl] * wsf[cl];
                atomicAdd(&y32[((size_t)b*T + qt*64 + rl)*C + h*HD + cl], val);
            }
}

// -----------------------------------------------------------------------------
extern "C" void kernel_launch(void* const* d_in, const int* in_sizes, int n_in,
                              void* d_out, int out_size, void* d_ws, size_t ws_size,
                              hipStream_t stream) {
    (void)in_sizes; (void)n_in; (void)out_size;
    const float* x      = (const float*)d_in[0];
    const float* t      = (const float*)d_in[1];
    const float* ln1_w  = (const float*)d_in[2];
    const float* ln1_b  = (const float*)d_in[3];
    const float* attn_w = (const float*)d_in[4];
    const float* attn_b = (const float*)d_in[5];
    const float* proj_w = (const float*)d_in[6];
    const float* proj_b = (const float*)d_in[7];
    const float* ln2_w  = (const float*)d_in[8];
    const float* ln2_b  = (const float*)d_in[9];
    const float* fc_w   = (const float*)d_in[10];
    const float* fc_b   = (const float*)d_in[11];
    const float* fc2_w  = (const float*)d_in[12];
    const float* fc2_b  = (const float*)d_in[13];
    float* out = (float*)d_out;

    // ---- workspace layout (121,482,240 bytes) ----
    if (ws_size < 121482240ull) return;
    char* wsb = (char*)d_ws;
    half_t*    c_h  = (half_t*)wsb;                          // 100,663,296
    _Float16*  qkvh = (_Float16*)(wsb + 100663296ull);       // 9,437,184: q|k|v head-major
    float*     y32  = (float*)(wsb + 110100480ull);          // 6,291,456
    _Float16*  xh   = (_Float16*)(wsb + 116391936ull);       // 3,407,872
    _Float16*  wbuf = (_Float16*)(wsb + 119799808ull);       // 1,277,952
    float*     eu   = (float*)(wsb + 121077760ull);          // BHT
    float*     ev   = eu   + BHT;
    float*     cacc = ev   + BHT;
    float*     sev  = cacc + BHT;                            // 12*33 (+pad)
    float*     wsuf = sev  + 1024;                           // 12*33*64
    // aliases:
    const _Float16* qh = qkvh;
    const _Float16* kh = qkvh + (size_t)(B*H) * T * 64;
    const _Float16* vh = qkvh + (size_t)2 * (B*H) * T * 64;
    _Float16* xn_h = xh;               // ln1 out -> qkv gemm in
    _Float16* hn_h = xh;               // ln2 out -> fc in (xh dead)
    float*    hb   = (float*)qkvh;     // proj out (qkvh dead after pv)
    _Float16* mb_h = (_Float16*)wsb;   // fc out (c dead after pv)

    const int M = B * T;   // 4096
    const int KP1 = 416;   // (C+1) padded to 32

    // ---- attention sub-block ----
    addtime_ln_f16<<<M, 256, 0, stream>>>(x, t, ln1_w, ln1_b, xn_h, KP1);
    convtrans_kernel<<<dim3(KP1/32, (3*C)/32), 256, 0, stream>>>(attn_w, wbuf, C+1, 3*C, KP1);
    mfma_gemm128<0, 1, _Float16, _Float16><<<dim3(3*C/128, M/128), 256, 0, stream>>>(
        xn_h, wbuf, attn_b, qkvh, M, 3*C, KP1);
    qk_tileA<<<dim3(528, B*H), 256, 0, stream>>>(qh, kh, c_h);

    // ---- multiplicative sinkhorn, fused passes ----
    zerof_kernel<<<BHT/256, 256, 0, stream>>>(cacc);
    norm_q_col<<<dim3(64, B*H), 256, 0, stream>>>(c_h, eu, cacc);      // q, eu0, colacc
    v_fin_full<<<B*H, 256, 0, stream>>>(cacc, eu, ev, sev);            // ev1 (+sev, cacc=0)
    row_col<<<dim3(64, B*H), 256, 0, stream>>>(c_h, ev, sev, eu, cacc);// eu2, colacc
    v_fin_full<<<B*H, 256, 0, stream>>>(cacc, eu, ev, sev);            // ev3
    row_col<<<dim3(64, B*H), 256, 0, stream>>>(c_h, ev, sev, eu, cacc);// eu4, colacc
    v_fin_full<<<B*H, 256, 0, stream>>>(cacc, eu, ev, sev);            // ev5

    wv_suffix_kernel<<<B*H, 256, 0, stream>>>(vh, ev, wsuf);
    zerof_kernel<<<(M*C)/256, 256, 0, stream>>>(y32);
    pv_split<<<dim3(T/64, 4, B*H), 256, 0, stream>>>(c_h, eu, ev, vh, wsuf, y32);

    convtrans_kernel<<<dim3(C/32, C/32), 256, 0, stream>>>(proj_w, wbuf, C, C, C);
    mfma_gemm<0, 0, float, float><<<dim3(C/64, M/64), 256, 0, stream>>>(
        y32, wbuf, proj_b, hb, M, C, C);

    // ---- MLP sub-block ----
    addtime_ln_f16<<<M, 256, 0, stream>>>(hb, t, ln2_w, ln2_b, hn_h, KP1);
    convtrans_kernel<<<dim3(KP1/32, (4*C)/32), 256, 0, stream>>>(fc_w, wbuf, C+1, 4*C, KP1);
    mfma_gemm128<1, 0, _Float16, _Float16><<<dim3(4*C/128, M/128), 256, 0, stream>>>(
        hn_h, wbuf, fc_b, mb_h, M, 4*C, KP1);
    convtrans_kernel<<<dim3((4*C)/32, C/32), 256, 0, stream>>>(fc2_w, wbuf, 4*C, C, 4*C);
    mfma_gemm<0, 0, _Float16, float><<<dim3(C/64, M/64), 256, 0, stream>>>(
        mb_h, wbuf, fc2_b, out, M, C, 4*C);
}